// Round 13
// baseline (499.290 us; speedup 1.0000x reference)
//
#include <hip/hip_runtime.h>

constexpr int T = 168;
constexpr int P = 16;
constexpr int H = 24;

typedef float v2f __attribute__((ext_vector_type(2)));

__device__ __forceinline__ v2f mk2(float a, float b) { v2f r; r[0] = a; r[1] = b; return r; }
__device__ __forceinline__ v2f bc2(float a)          { v2f r; r[0] = a; r[1] = a; return r; }
__device__ __forceinline__ v2f pkfma(v2f a, v2f b, v2f c) {
    return __builtin_elementwise_fma(a, b, c);   // v_pk_fma_f32
}

__device__ __forceinline__ float rcp_f(float x) { return __builtin_amdgcn_rcpf(x); }
__device__ __forceinline__ float sigm_f(float x) { return rcp_f(1.f + __expf(-x)); }
__device__ __forceinline__ float tanh_fast(float x) {
    return fmaf(2.f, rcp_f(1.f + __expf(-2.f * x)), -1.f);
}

#define KEEP2(v) asm volatile("" : "+v"(v))
// Compiler reorder fence ONLY — same-wave DS ops execute in order.
#define SCHED_FENCE() asm volatile("" ::: "memory")
#define LDS_SYNC() asm volatile("s_waitcnt lgkmcnt(0)" ::: "memory")

// Produce (lower-half broadcast, upper-half broadcast) of v across the wave
// via v_permlane32_swap_b32 on the VALU pipe (keeps broadcasts OFF the
// saturated LDS pipe). Mapping established by elimination across R9-R12:
//  - R9/R10 asm "+v"(d),"+v"(s2): allocator COALESCED d,s2 -> self-swap UB.
//  - R12 "%0,%0": degenerates to single-half broadcast (error signature
//    proved broadcast(v.lo) wins the tied-register race AND that the rest of
//    the dataflow is correct — row A came out exact).
//  - R11 builtin with {updup=r[0], lowdup=r[1]} failed with swapped-halves
//    signature -> the correct mapping is the complement:
#define HAVE_PLSWAP __has_builtin(__builtin_amdgcn_permlane32_swap)
__device__ __forceinline__ void swap32(float v, float& lowdup, float& updup) {
#if HAVE_PLSWAP
    auto r = __builtin_amdgcn_permlane32_swap(__float_as_uint(v), __float_as_uint(v),
                                              false, false);
    lowdup = __uint_as_float(r[0]);   // lower-half value in all lanes
    updup  = __uint_as_float(r[1]);   // upper-half value in all lanes
#else
    int o = __shfl(__float_as_int(v), (int)(threadIdx.x & 63) ^ 32);
    float ov = __int_as_float(o);
    bool lo = ((threadIdx.x & 63) < 32);
    lowdup = lo ? v : ov;
    updup  = lo ? ov : v;
#endif
}

// Read quad k of arr[2][32] for BOTH rows with one ds_read (lanes<32 row0,
// lanes>=32 row1) + 4 permlane swaps. The two wave-halves hit addresses 128 B
// apart -> same banks, 2-way conflict = free (m136).
__device__ __forceinline__ void quad_both(const float* myrow, const float* row0,
                                          const float* row1, int k,
                                          float4& qa, float4& qb) {
#if HAVE_PLSWAP
    float4 q = ((const float4*)myrow)[k];
    swap32(q.x, qa.x, qb.x);
    swap32(q.y, qa.y, qb.y);
    swap32(q.z, qa.z, qb.z);
    swap32(q.w, qa.w, qb.w);
#else
    qa = ((const float4*)row0)[k];
    qb = ((const float4*)row1)[k];
#endif
}

// 2 rows/wave, 2 waves/SIMD (forced by 176-float weight residency; R7 proved
// 1 wave/SIMD fatal). Gate pairs: lanes 0..23 = {i,g} of unit u; lanes
// 32..55 = {f,o} (32-offset so cross-half exchange = v_permlane32_swap on the
// VALU pipe, not ds_bpermute on the saturated LDS pipe). Lanes 24..31/56..63
// idle-dup. c/h state updates are valid on the upper half.
__global__ __attribute__((amdgpu_flat_work_group_size(64, 64),
                          amdgpu_waves_per_eu(2, 2)))
void lstm2_swp(const float* __restrict__ x,
               const float* __restrict__ Wih1, const float* __restrict__ Whh1,
               const float* __restrict__ bih1, const float* __restrict__ bhh1,
               const float* __restrict__ Wih2, const float* __restrict__ Whh2,
               const float* __restrict__ bih2, const float* __restrict__ bhh2,
               const float* __restrict__ W1, const float* __restrict__ b1,
               const float* __restrict__ W2, const float* __restrict__ b2,
               float* __restrict__ out)
{
    const int lane  = threadIdx.x & 63;
    const int inner = lane & 31;
    const int half  = lane >> 5;                    // 0: {i,g}, 1: {f,o}
    const int u     = (inner < 24) ? inner : inner - 8;   // dup for idle lanes
    const int q0    = half ? H + u     : u;         // f : i
    const int q1    = half ? 3 * H + u : 2 * H + u; // o : g
    const int rowA  = blockIdx.x * 2;

    // ---- packed weights: 88 v2f = 176 floats ----
    v2f wx[P], wh[H], vx[H], vh[H];
    #pragma unroll
    for (int k = 0; k < P; ++k) wx[k] = mk2(Wih1[q0 * P + k], Wih1[q1 * P + k]);
    #pragma unroll
    for (int k = 0; k < H; ++k) wh[k] = mk2(Whh1[q0 * H + k], Whh1[q1 * H + k]);
    #pragma unroll
    for (int k = 0; k < H; ++k) vx[k] = mk2(Wih2[q0 * H + k], Wih2[q1 * H + k]);
    #pragma unroll
    for (int k = 0; k < H; ++k) vh[k] = mk2(Whh2[q0 * H + k], Whh2[q1 * H + k]);
    v2f bias1 = mk2(bih1[q0] + bhh1[q0], bih1[q1] + bhh1[q1]);
    v2f bias2 = mk2(bih2[q0] + bhh2[q0], bih2[q1] + bhh2[q1]);
    #pragma unroll
    for (int k = 0; k < P; ++k) KEEP2(wx[k]);
    #pragma unroll
    for (int k = 0; k < H; ++k) { KEEP2(wh[k]); KEEP2(vx[k]); KEEP2(vh[k]); }
    KEEP2(bias1); KEEP2(bias2);

    __shared__ __align__(16) float h1s[2][32];
    __shared__ __align__(16) float t1s[2][32];
    __shared__ __align__(16) float h2s[2][32];
    __shared__ __align__(16) float hd [2][16];

    if (inner < 24) { h1s[half][inner] = 0.f; h2s[half][inner] = 0.f; }
    SCHED_FENCE();

    const float* __restrict__ xA = x + (size_t)rowA * T * P;        // uniform
    const float* __restrict__ xB = x + (size_t)(rowA + 1) * T * P;  // uniform

    // x(0) prefetch
    float4 sxA[4], sxB[4];
    #pragma unroll
    for (int j = 0; j < 4; ++j) { sxA[j] = ((const float4*)xA)[j]; sxB[j] = ((const float4*)xB)[j]; }

    const float* mh1 = &h1s[half][0];
    const float* mt1 = &t1s[half][0];
    const float* mh2 = &h2s[half][0];

    float c1A = 0.f, c1B = 0.f, c2A = 0.f, c2B = 0.f;

    for (int t = 0; t < T; ++t) {
        // ===== layer 1 gates =====
        v2f gA = bias1, gB = bias1;
        #pragma unroll
        for (int j = 0; j < 4; ++j) {
            gA = pkfma(bc2(sxA[j].x), wx[4*j],   gA);  gB = pkfma(bc2(sxB[j].x), wx[4*j],   gB);
            gA = pkfma(bc2(sxA[j].y), wx[4*j+1], gA);  gB = pkfma(bc2(sxB[j].y), wx[4*j+1], gB);
            gA = pkfma(bc2(sxA[j].z), wx[4*j+2], gA);  gB = pkfma(bc2(sxB[j].z), wx[4*j+2], gB);
            gA = pkfma(bc2(sxA[j].w), wx[4*j+3], gA);  gB = pkfma(bc2(sxB[j].w), wx[4*j+3], gB);
        }
        #pragma unroll
        for (int k = 0; k < H / 4; ++k) {
            float4 ha, hb;
            quad_both(mh1, &h1s[0][0], &h1s[1][0], k, ha, hb);
            gA = pkfma(bc2(ha.x), wh[4*k],   gA);  gB = pkfma(bc2(hb.x), wh[4*k],   gB);
            gA = pkfma(bc2(ha.y), wh[4*k+1], gA);  gB = pkfma(bc2(hb.y), wh[4*k+1], gB);
            gA = pkfma(bc2(ha.z), wh[4*k+2], gA);  gB = pkfma(bc2(hb.z), wh[4*k+2], gB);
            gA = pkfma(bc2(ha.w), wh[4*k+3], gA);  gB = pkfma(bc2(hb.w), wh[4*k+3], gB);
        }
        // activations: lower {i,g}: a0=sigm(i), a1=tanh(g); upper {f,o}: sigm both
        float a0A = sigm_f(gA[0]);
        float pxA = half ? gA[1] : gA[1] + gA[1];
        float svA = sigm_f(pxA);
        float a1A = half ? svA : svA + svA - 1.f;
        float a0B = sigm_f(gB[0]);
        float pxB = half ? gB[1] : gB[1] + gB[1];
        float svB = sigm_f(pxB);
        float a1B = half ? svB : svB + svB - 1.f;
        // p = i*tanh(g) lives on the lower half; broadcast it to all lanes
        float pA_lo, pA_up, pB_lo, pB_up;
        swap32(a0A * a1A, pA_lo, pA_up);
        swap32(a0B * a1B, pB_lo, pB_up);
        // state update (valid on upper half: a0=f, a1=o there)
        c1A = fmaf(a0A, c1A, pA_lo);
        c1B = fmaf(a0B, c1B, pB_lo);
        float hvA = a1A * tanh_fast(c1A);
        float hvB = a1B * tanh_fast(c1B);
        float thA = tanh_fast(hvA);
        float thB = tanh_fast(hvB);
        if (half == 1 && inner < 24) {
            h1s[0][inner] = hvA;  h1s[1][inner] = hvB;
            t1s[0][inner] = thA;  t1s[1][inner] = thB;
        }
        SCHED_FENCE();

        // ===== layer 2 gates =====
        v2f fA = bias2, fB = bias2;
        #pragma unroll
        for (int k = 0; k < H / 4; ++k) {
            float4 ta, tb;
            quad_both(mt1, &t1s[0][0], &t1s[1][0], k, ta, tb);
            fA = pkfma(bc2(ta.x), vx[4*k],   fA);  fB = pkfma(bc2(tb.x), vx[4*k],   fB);
            fA = pkfma(bc2(ta.y), vx[4*k+1], fA);  fB = pkfma(bc2(tb.y), vx[4*k+1], fB);
            fA = pkfma(bc2(ta.z), vx[4*k+2], fA);  fB = pkfma(bc2(tb.z), vx[4*k+2], fB);
            fA = pkfma(bc2(ta.w), vx[4*k+3], fA);  fB = pkfma(bc2(tb.w), vx[4*k+3], fB);
        }
        #pragma unroll
        for (int k = 0; k < H / 4; ++k) {
            float4 ha, hb;
            quad_both(mh2, &h2s[0][0], &h2s[1][0], k, ha, hb);
            fA = pkfma(bc2(ha.x), vh[4*k],   fA);  fB = pkfma(bc2(hb.x), vh[4*k],   fB);
            fA = pkfma(bc2(ha.y), vh[4*k+1], fA);  fB = pkfma(bc2(hb.y), vh[4*k+1], fB);
            fA = pkfma(bc2(ha.z), vh[4*k+2], fA);  fB = pkfma(bc2(hb.z), vh[4*k+2], fB);
            fA = pkfma(bc2(ha.w), vh[4*k+3], fA);  fB = pkfma(bc2(hb.w), vh[4*k+3], fB);
        }
        // x prefetch for t+1 (overlaps activations/state math below)
        {
            int tn = (t + 1 < T) ? t + 1 : t;
            const float4* pA4 = (const float4*)(xA + (size_t)tn * P);
            const float4* pB4 = (const float4*)(xB + (size_t)tn * P);
            #pragma unroll
            for (int j = 0; j < 4; ++j) { sxA[j] = pA4[j]; sxB[j] = pB4[j]; }
        }
        // layer-2 activations + update
        float b0A = sigm_f(fA[0]);
        float qxA = half ? fA[1] : fA[1] + fA[1];
        float swA = sigm_f(qxA);
        float b1Av = half ? swA : swA + swA - 1.f;
        float b0B = sigm_f(fB[0]);
        float qxB = half ? fB[1] : fB[1] + fB[1];
        float swB = sigm_f(qxB);
        float b1Bv = half ? swB : swB + swB - 1.f;
        float rA_lo, rA_up, rB_lo, rB_up;
        swap32(b0A * b1Av, rA_lo, rA_up);
        swap32(b0B * b1Bv, rB_lo, rB_up);
        c2A = fmaf(b0A, c2A, rA_lo);
        c2B = fmaf(b0B, c2B, rB_lo);
        float h2A = b1Av * tanh_fast(c2A);
        float h2B = b1Bv * tanh_fast(c2B);
        if (half == 1 && inner < 24) {
            h2s[0][inner] = h2A;  h2s[1][inner] = h2B;
        }
        SCHED_FENCE();
    }

    LDS_SYNC();   // one-time drain before the head

    // ---- head: tanh -> fc1(16, relu) -> fc2(24); lanes<32 row A, >=32 row B
    if (inner < 24) t1s[half][inner] = tanh_fast(h2s[half][inner]);
    SCHED_FENCE();
    {
        const int l16 = inner & 15;
        float w1r[H];
        #pragma unroll
        for (int j = 0; j < H; ++j) w1r[j] = W1[l16 * H + j];
        float acc = b1[l16];
        #pragma unroll
        for (int k = 0; k < H / 4; ++k) {
            float4 q = ((const float4*)&t1s[half][0])[k];
            acc = fmaf(q.x, w1r[4*k],   acc);
            acc = fmaf(q.y, w1r[4*k+1], acc);
            acc = fmaf(q.z, w1r[4*k+2], acc);
            acc = fmaf(q.w, w1r[4*k+3], acc);
        }
        if (inner < 16) hd[half][inner] = fmaxf(acc, 0.f);
    }
    SCHED_FENCE();
    {
        float w2r[16];
        #pragma unroll
        for (int j = 0; j < 16; ++j) w2r[j] = W2[u * 16 + j];
        float acc = b2[u];
        #pragma unroll
        for (int k = 0; k < 4; ++k) {
            float4 q = ((const float4*)&hd[half][0])[k];
            acc = fmaf(q.x, w2r[4*k],   acc);
            acc = fmaf(q.y, w2r[4*k+1], acc);
            acc = fmaf(q.z, w2r[4*k+2], acc);
            acc = fmaf(q.w, w2r[4*k+3], acc);
        }
        if (inner < 24) out[(size_t)(rowA + half) * H + inner] = acc;
    }
}

extern "C" void kernel_launch(void* const* d_in, const int* in_sizes, int n_in,
                              void* d_out, int out_size, void* d_ws, size_t ws_size,
                              hipStream_t stream)
{
    const float* x    = (const float*)d_in[0];
    const float* Wih1 = (const float*)d_in[1];
    const float* Whh1 = (const float*)d_in[2];
    const float* bih1 = (const float*)d_in[3];
    const float* bhh1 = (const float*)d_in[4];
    const float* Wih2 = (const float*)d_in[5];
    const float* Whh2 = (const float*)d_in[6];
    const float* bih2 = (const float*)d_in[7];
    const float* bhh2 = (const float*)d_in[8];
    const float* W1   = (const float*)d_in[9];
    const float* b1   = (const float*)d_in[10];
    const float* W2   = (const float*)d_in[11];
    const float* b2   = (const float*)d_in[12];
    float* out = (float*)d_out;

    const int B = in_sizes[0] / (T * P);             // 4096
    hipLaunchKernelGGL(lstm2_swp, dim3(B / 2), dim3(64), 0, stream,
                       x, Wih1, Whh1, bih1, bhh1, Wih2, Whh2, bih2, bhh2,
                       W1, b1, W2, b2, out);
}